// Round 1
// baseline (236.555 us; speedup 1.0000x reference)
//
#include <hip/hip_runtime.h>

// BehaviorFluidFlow: falling-sand fluid pass on world (16,20,512,512) fp32.
// All neighbor interaction is roll(±1) along W only -> process one (b,h) row
// per workgroup, entirely in LDS, 10 sequential (elem, dir) passes.
//
// Identity used: becomes_right[w] == becomes_left[w+sh] (verified from the
// roll algebra), so we materialize only the becomes_left plane per pass.
// new_fm is per-pixel only -> registers.

#define WW   512
#define CCH  20
#define DENS 14   // NUM_ELEMENTS
#define GRAV 15   // NUM_ELEMENTS+1
#define FMC  16   // NUM_ELEMENTS+2

__global__ __launch_bounds__(256) void fluid_row_kernel(
    const float* __restrict__ world_in,
    const float* __restrict__ rand_movement,
    const float* __restrict__ did_gravity,
    float* __restrict__ world_out)
{
    __shared__ float s_world[CCH][WW];
    __shared__ float s_bl[WW];

    const int tid = threadIdx.x;
    const int row = blockIdx.x;        // b*512 + h
    const int b   = row >> 9;
    const int h   = row & 511;

    const size_t chan_stride = (size_t)512 * 512;
    const size_t world_row   = ((size_t)(b * CCH) * 512 + (size_t)h) * 512;
    const size_t scalar_row  = ((size_t)b * 512 + (size_t)h) * 512;

    // ---- stage world row into LDS (coalesced, 2 px/thread/channel) ----
    #pragma unroll
    for (int c = 0; c < CCH; ++c) {
        const float* src = world_in + world_row + (size_t)c * chan_stride;
        s_world[c][tid]       = src[tid];
        s_world[c][tid + 256] = src[tid + 256];
    }
    const float rm0 = rand_movement[scalar_row + tid];
    const float rm1 = rand_movement[scalar_row + tid + 256];
    const bool ndg0 = did_gravity[scalar_row + tid]       <= 0.0f;
    const bool ndg1 = did_gravity[scalar_row + tid + 256] <= 0.0f;
    float nf0 = 0.0f, nf1 = 0.0f;   // new_fm accumulator, per own pixel

    __syncthreads();

    const int elems[5] = {0, 3, 4, 10, 11};

    #pragma unroll 1
    for (int ei = 0; ei < 5; ++ei) {
        const int elem = elems[ei];
        #pragma unroll 1
        for (int fl = 1; fl >= 0; --fl) {       // fall_left = True, then False
            const int   sh = fl ? 1 : -1;
            const float k  = fl ? 2.0f : -2.0f;

            // ---- phase 1: becomes_left into s_bl ----
            float bl[2];
            #pragma unroll
            for (int p = 0; p < 2; ++p) {
                const int w  = tid + p * 256;
                const int wm = (w - sh) & 511;
                const float rm  = p ? rm1 : rm0;
                const float nf  = p ? nf1 : nf0;
                const bool  ndg = p ? ndg1 : ndg0;
                const bool fall_dir = (rm + s_world[FMC][w] + nf) > 0.5f;
                const bool imf = fl ? fall_dir : !fall_dir;
                const bool ise = (s_world[elem][w] == 1.0f);
                const bool ldl = (s_world[DENS][w] - s_world[DENS][wm]) > 0.0f;
                const bool isg = (s_world[GRAV][w] == 1.0f);
                const bool ilg = (s_world[GRAV][wm] == 1.0f) && isg;
                const bool bleft = imf && ise && ndg && ldl && ilg;
                bl[p] = bleft ? 1.0f : 0.0f;
                s_bl[w] = bl[p];
            }
            __syncthreads();

            // ---- phase 2: gather blended values into registers ----
            float nv[2][CCH];
            bool  changed[2];
            #pragma unroll
            for (int p = 0; p < 2; ++p) {
                const int w  = tid + p * 256;
                const int wm = (w - sh) & 511;
                const int wp = (w + sh) & 511;
                const float a  = bl[p];
                const float bb = s_bl[wp];     // becomes_right[w] = becomes_left[w+sh]
                if (p) nf1 += bb * k; else nf0 += bb * k;
                changed[p] = (a != 0.0f) || (bb != 0.0f);
                if (changed[p]) {
                    const float ca = (1.0f - a) * (1.0f - bb);
                    #pragma unroll
                    for (int c = 0; c < CCH; ++c)
                        nv[p][c] = ca * s_world[c][w] + a * s_world[c][wm]
                                 + bb * s_world[c][wp];
                }
            }
            __syncthreads();

            // ---- phase 3: write back ----
            #pragma unroll
            for (int p = 0; p < 2; ++p) {
                if (changed[p]) {
                    const int w = tid + p * 256;
                    #pragma unroll
                    for (int c = 0; c < CCH; ++c)
                        s_world[c][w] = nv[p][c];
                }
            }
            __syncthreads();
        }
    }

    // ---- write out: fm channel is new_fm; rest from LDS ----
    #pragma unroll
    for (int c = 0; c < CCH; ++c) {
        float* dst = world_out + world_row + (size_t)c * chan_stride;
        dst[tid]       = (c == FMC) ? nf0 : s_world[c][tid];
        dst[tid + 256] = (c == FMC) ? nf1 : s_world[c][tid + 256];
    }
}

extern "C" void kernel_launch(void* const* d_in, const int* in_sizes, int n_in,
                              void* d_out, int out_size, void* d_ws, size_t ws_size,
                              hipStream_t stream) {
    const float* world = (const float*)d_in[0];
    const float* rm    = (const float*)d_in[1];
    const float* ri    = (const float*)d_in[2];
    const float* re    = (const float*)d_in[3];
    const float* vf    = (const float*)d_in[4];
    const float* dg    = (const float*)d_in[5];
    float* out = (float*)d_out;

    const size_t BHW = (size_t)16 * 512 * 512;       // 4,194,304
    size_t off = BHW * CCH;                          // world
    float* out_rm = out + off; off += BHW;
    float* out_ri = out + off; off += BHW;
    float* out_re = out + off; off += BHW;
    float* out_vf = out + off; off += BHW * 2;
    float* out_dg = out + off;

    // pass-through outputs
    hipMemcpyAsync(out_rm, rm, BHW * 4, hipMemcpyDeviceToDevice, stream);
    hipMemcpyAsync(out_ri, ri, BHW * 4, hipMemcpyDeviceToDevice, stream);
    hipMemcpyAsync(out_re, re, BHW * 4, hipMemcpyDeviceToDevice, stream);
    hipMemcpyAsync(out_vf, vf, BHW * 8, hipMemcpyDeviceToDevice, stream);
    hipMemcpyAsync(out_dg, dg, BHW * 4, hipMemcpyDeviceToDevice, stream);

    dim3 grid(16 * 512), block(256);
    fluid_row_kernel<<<grid, block, 0, stream>>>(world, rm, dg, out);
}

// Round 2
// 192.906 us; speedup vs baseline: 1.2263x; 1.2263x over previous
//
#include <hip/hip_runtime.h>

// BehaviorFluidFlow: falling-sand fluid pass on world (16,20,512,512) fp32.
// One workgroup per (b,h) row; whole row lives in LDS; 10 sequential
// (elem, fall_dir) passes. becomes_right[w] == becomes_left[w+sh], so only
// one bl-plane per pass. new_fm is per-pixel -> registers.
// Fused: this kernel also copies the 5 passthrough outputs (its row slice),
// so the whole op is a single launch.

#define WW   512
#define CCH  20
#define DENS 14   // NUM_ELEMENTS
#define GRAV 15   // NUM_ELEMENTS+1
#define FMC  16   // NUM_ELEMENTS+2

__global__ __launch_bounds__(256) void fluid_fused_kernel(
    const float* __restrict__ world_in,
    const float* __restrict__ rand_movement,
    const float* __restrict__ rand_interact,
    const float* __restrict__ rand_element,
    const float* __restrict__ velocity_field,
    const float* __restrict__ did_gravity,
    float* __restrict__ out)
{
    __shared__ __align__(16) float s_world[CCH][WW];
    __shared__ float s_bl[WW];

    const int tid = threadIdx.x;
    const int row = blockIdx.x;        // b*512 + h
    const int b   = row >> 9;
    const int h   = row & 511;

    const size_t BHW        = (size_t)16 * 512 * 512;
    const size_t CH         = (size_t)512 * 512;
    const size_t scalar_row = ((size_t)b * 512 + h) * 512;
    const size_t world_row0 = ((size_t)b * CCH * 512 + h) * 512;
    const size_t vf_row0    = ((size_t)b * 2 * 512 + h) * 512;
    const size_t vf_row1    = vf_row0 + CH;

    // ---- stage world row into LDS: flat float4 over [20][512] ----
    float4* s_flat = (float4*)&s_world[0][0];
    #pragma unroll
    for (int it = 0; it < 10; ++it) {
        const int q = tid + it * 256;          // 0..2559
        const int c = q >> 7, i = q & 127;
        s_flat[q] = ((const float4*)(world_in + world_row0 + (size_t)c * CH))[i];
    }

    // ---- passthrough copies for this row (independent of LDS) ----
    {
        const int i  = tid & 127;
        const int hi = tid >> 7;   // 0 or 1 (half-block split, wave-uniform)
        {   // rm | ri
            const float* s = (hi ? rand_interact : rand_movement) + scalar_row;
            float*       d = out + (hi ? (size_t)21 : (size_t)20) * BHW + scalar_row;
            ((float4*)d)[i] = ((const float4*)s)[i];
        }
        {   // re | vf ch0
            const float* s = hi ? velocity_field + vf_row0 : rand_element + scalar_row;
            float*       d = hi ? out + (size_t)23 * BHW + vf_row0
                                : out + (size_t)22 * BHW + scalar_row;
            ((float4*)d)[i] = ((const float4*)s)[i];
        }
        {   // vf ch1 | dg
            const float* s = hi ? did_gravity + scalar_row : velocity_field + vf_row1;
            float*       d = hi ? out + (size_t)25 * BHW + scalar_row
                                : out + (size_t)23 * BHW + vf_row1;
            ((float4*)d)[i] = ((const float4*)s)[i];
        }
    }

    const float rm0 = rand_movement[scalar_row + tid];
    const float rm1 = rand_movement[scalar_row + tid + 256];
    const bool ndg0 = did_gravity[scalar_row + tid]       <= 0.0f;
    const bool ndg1 = did_gravity[scalar_row + tid + 256] <= 0.0f;
    float nf0 = 0.0f, nf1 = 0.0f;   // new_fm accumulator, per own pixel

    __syncthreads();

    const int elems[5] = {0, 3, 4, 10, 11};

    #pragma unroll 1
    for (int ei = 0; ei < 5; ++ei) {
        const int elem = elems[ei];
        #pragma unroll 1
        for (int fl = 1; fl >= 0; --fl) {       // fall_left = True, then False
            const int   sh = fl ? 1 : -1;
            const float k  = fl ? 2.0f : -2.0f;

            // ---- phase 1: becomes_left into s_bl ----
            float bl[2];
            #pragma unroll
            for (int p = 0; p < 2; ++p) {
                const int w  = tid + p * 256;
                const int wm = (w - sh) & 511;
                const float rm  = p ? rm1 : rm0;
                const float nf  = p ? nf1 : nf0;
                const bool  ndg = p ? ndg1 : ndg0;
                const bool fall_dir = (rm + s_world[FMC][w] + nf) > 0.5f;
                const bool imf = fl ? fall_dir : !fall_dir;
                const bool ise = (s_world[elem][w] == 1.0f);
                const bool ldl = (s_world[DENS][w] - s_world[DENS][wm]) > 0.0f;
                const bool isg = (s_world[GRAV][w] == 1.0f);
                const bool ilg = (s_world[GRAV][wm] == 1.0f) && isg;
                const bool bleft = imf && ise && ndg && ldl && ilg;
                bl[p] = bleft ? 1.0f : 0.0f;
                s_bl[w] = bl[p];
            }
            __syncthreads();

            // ---- phase 2: gather blended values into registers ----
            float nv[2][CCH];
            bool  changed[2];
            #pragma unroll
            for (int p = 0; p < 2; ++p) {
                const int w  = tid + p * 256;
                const int wm = (w - sh) & 511;
                const int wp = (w + sh) & 511;
                const float a  = bl[p];
                const float bb = s_bl[wp];     // becomes_right[w] = becomes_left[w+sh]
                if (p) nf1 += bb * k; else nf0 += bb * k;
                changed[p] = (a != 0.0f) || (bb != 0.0f);
                if (changed[p]) {
                    const float ca = (1.0f - a) * (1.0f - bb);
                    #pragma unroll
                    for (int c = 0; c < CCH; ++c)
                        nv[p][c] = ca * s_world[c][w] + a * s_world[c][wm]
                                 + bb * s_world[c][wp];
                }
            }
            __syncthreads();

            // ---- phase 3: write back ----
            #pragma unroll
            for (int p = 0; p < 2; ++p) {
                if (changed[p]) {
                    const int w = tid + p * 256;
                    #pragma unroll
                    for (int c = 0; c < CCH; ++c)
                        s_world[c][w] = nv[p][c];
                }
            }
            __syncthreads();
        }
    }

    // ---- deposit new_fm into LDS, then flat float4 store of all channels ----
    s_world[FMC][tid]       = nf0;
    s_world[FMC][tid + 256] = nf1;
    __syncthreads();

    #pragma unroll
    for (int it = 0; it < 10; ++it) {
        const int q = tid + it * 256;
        const int c = q >> 7, i = q & 127;
        ((float4*)(out + world_row0 + (size_t)c * CH))[i] = s_flat[q];
    }
}

extern "C" void kernel_launch(void* const* d_in, const int* in_sizes, int n_in,
                              void* d_out, int out_size, void* d_ws, size_t ws_size,
                              hipStream_t stream) {
    const float* world = (const float*)d_in[0];
    const float* rm    = (const float*)d_in[1];
    const float* ri    = (const float*)d_in[2];
    const float* re    = (const float*)d_in[3];
    const float* vf    = (const float*)d_in[4];
    const float* dg    = (const float*)d_in[5];
    float* out = (float*)d_out;

    dim3 grid(16 * 512), block(256);
    fluid_fused_kernel<<<grid, block, 0, stream>>>(world, rm, ri, re, vf, dg, out);
}